// Round 11
// baseline (157.412 us; speedup 1.0000x reference)
//
#include <hip/hip_runtime.h>

// Conv2D 15x15 valid, 4096^2 fp32 -> 4082^2 fp32, via bf16 MFMA Toeplitz-band.
//
// R10: DMA-PIPELINED multi-tile blocks -- global_load_lds prefetch that
// CANNOT be sunk by the compiler (no VGPR dest; ordered only by vmcnt).
//
// Theory: all per-pipe levers falsified (R2 conflicts, R3/R8 LDS, R4 B-path,
// R5 barrier, R7 reg-prefetch, R9 stores); every variant pins at
// dur ~= hbm_bytes / 2.4 TB/s with all pipes <40%. Arithmetic: per block
// ~29 KB HBM in 7.5k cy, emitted in two bursts around a ~4k-cy memory-idle
// compute phase; phase-aligned co-resident blocks -> CU memory duty ~40%;
// 0.40 x 6.3 TB/s = 2.5 TB/s == observed. R7's register prefetch failed
// because LLVM sinks loads toward uses under pressure (VGPR=64 = exactly
// v[]+base); DMA prefetch is sink-proof by construction.
//
// Per iter (TJ=4 tiles/block): issue DMA(tile j+1 -> fp32 stage LDS);
// compute+store tile j from bf16[cur] (DMA flies under 60 MFMAs);
// vmcnt(0); convert stage -> bf16[nxt] (each wave converts its OWN DMA'd
// items, so own-wave vmcnt suffices, no pre-convert barrier); one
// __syncthreads per iter.
// Hazard proof (single barrier): stage written by DMA(j+1) @iter-j-top,
// read by convert @iter-j-end [same wave vmcnt]; overwritten by DMA(j+2)
// @iter-j+1-top, which is after the iter-j barrier that all converts
// precede. bf16[nxt] written pre-barrier iter j, read post-barrier iter
// j+1. bf16[cur] read iter j, was written pre-barrier iter j-1.
//
// x-edge blocks (bx==63, 16/1024): register path (needs element clamping,
// DMA can't replicate). y-clamp folds into per-lane DMA SOURCE addresses
// (global src is per-lane; LDS dest stays linear base+lane*16).

#define HIN 4096
#define WIN 4096
#define KH 15
#define KW 15
#define OH (HIN - KH + 1)  // 4082
#define OW (WIN - KW + 1)  // 4082

#define BX 64
#define BY 64
#define XROWS (BY + KH - 1)     // 78 staged input rows
#define XCOLS 80                // staged input cols (64 + 14, padded to 80)
#define LDSW 88                 // bf16 row stride (176 B -> bank skew, proven)
#define NSHB (XROWS * LDSW)     // 6864 shorts = 13728 B per bf16 buffer
#define NSTG (XROWS * XCOLS)    // 6240 floats = 24960 B fp32 stage buffer
#define NB4 (XCOLS / 4)         // 20 float4 per staged row
#define NITEM (XROWS * NB4)     // 1560 staging items per tile
#define TJ 4                    // y-tiles per block
#define GRIDY 16                // grid.y; tile stride in tile space

typedef short bf16x8 __attribute__((ext_vector_type(8)));
typedef float f32x4  __attribute__((ext_vector_type(4)));

// async 16B global->LDS DMA (gfx950): no VGPR dest, counts in vmcnt.
// LDS dest is wave-uniform base + lane*16 (we pass per-lane addr; lane 0
// is always the first active lane here, so base is correct).
#define GLD_LDS16(gp, lp)                                                    \
    __builtin_amdgcn_global_load_lds(                                        \
        (const __attribute__((address_space(1))) void*)(gp),                 \
        (__attribute__((address_space(3))) void*)(lp), 16, 0, 0)

static __device__ inline short f2bf(float f) {  // fp32 -> bf16 RNE
    unsigned u = __float_as_uint(f);
    u += 0x7fffu + ((u >> 16) & 1u);
    return (short)(u >> 16);
}

// ---- prep: build B-fragment table (15 kh x 64 lanes x bf16x8) once in ws ----
// 16x16x32 B-operand layout: lane L holds B[k=(L>>4)*8+j][n=L&15], j=0..7,
// with B[k][n] = w[kh][k-n] (0 outside band).
__global__ void conv2d_btab(const float* __restrict__ w, short* __restrict__ btab) {
    const int e = blockIdx.x * 256 + threadIdx.x;
    if (e >= KH * 64) return;
    const int kh = e >> 6;
    const int L  = e & 63;
    const int n  = L & 15;
    const int q  = L >> 4;
    bf16x8 bv;
#pragma unroll
    for (int j = 0; j < 8; ++j) {
        const int d = q * 8 + j - n;          // k - n
        bv[j] = (d >= 0 && d < KW) ? f2bf(w[kh * KW + d]) : (short)0;
    }
    *reinterpret_cast<bf16x8*>(&btab[(size_t)e * 8]) = bv;
}

__global__ __launch_bounds__(256, 4)
void conv2d_mfma(const float* __restrict__ x,
                 const short* __restrict__ btab,
                 const float* __restrict__ bias,
                 float* __restrict__ out) {
    __shared__ __align__(16) float stage[NSTG];   // 24960 B DMA destination
    __shared__ __align__(16) short bufA[NSHB];    // 13728 B bf16 tile (even j)
    __shared__ __align__(16) short bufB[NSHB];    // 13728 B bf16 tile (odd j)

    const int tid  = threadIdx.x;
    const int lane = tid & 63;
    const int wv   = tid >> 6;
    const int ox0  = blockIdx.x * BX;
    const bool xint = (ox0 + XCOLS <= WIN);       // bx < 63

    // ---- DMA-issue a tile's 78x80 fp32 rows into stage (interior-x only) ----
    auto dma_issue = [&](int iy0) {
#pragma unroll
        for (int i = 0; i < 7; ++i) {
            const int f = tid + 256 * i;          // = i*256 + wv*64 + lane
            if (f < NITEM) {                      // per-lane exec mask; lane0 active
                const int r  = f / NB4;
                const int c4 = (f - r * NB4) * 4;
                int gy = iy0 + r;
                if (gy > HIN - 1) gy = HIN - 1;   // clamped rows feed masked outputs
                GLD_LDS16(&x[(size_t)gy * WIN + ox0 + c4], &stage[(size_t)f * 4]);
            }
        }
        __builtin_amdgcn_sched_barrier(0);        // pin issues before compute
    };

    // ---- convert own-wave DMA'd items: fp32 stage -> bf16 buf ----
    auto convert = [&](short* buf) {
        asm volatile("s_waitcnt vmcnt(0)" ::: "memory");  // own DMAs landed
        __builtin_amdgcn_sched_barrier(0);
#pragma unroll
        for (int i = 0; i < 7; ++i) {
            const int f = tid + 256 * i;          // same items this wave DMA'd
            if (f < NITEM) {
                const int r  = f / NB4;
                const int c4 = (f - r * NB4) * 4;
                const float4 v = *reinterpret_cast<const float4*>(&stage[(size_t)f * 4]);
                short4 s;
                s.x = f2bf(v.x); s.y = f2bf(v.y); s.z = f2bf(v.z); s.w = f2bf(v.w);
                *reinterpret_cast<short4*>(&buf[r * LDSW + c4]) = s;   // ds_write_b64
            }
        }
    };

    // ---- x-edge fallback (bx==63): clamped register path into buf ----
    auto edge_stage = [&](int iy0, short* buf) {
        for (int f = tid; f < NITEM; f += 256) {
            const int r  = f / NB4;
            const int c4 = (f - r * NB4) * 4;
            int gy = iy0 + r;
            if (gy > HIN - 1) gy = HIN - 1;
            const float* row = &x[(size_t)gy * WIN];
            const int gx = ox0 + c4;
            float4 v;
            if (gx + 3 <= WIN - 1) {
                v = *reinterpret_cast<const float4*>(&row[gx]);
            } else {
                const int x0 = (gx + 0 > WIN - 1) ? WIN - 1 : gx + 0;
                const int x1 = (gx + 1 > WIN - 1) ? WIN - 1 : gx + 1;
                const int x2 = (gx + 2 > WIN - 1) ? WIN - 1 : gx + 2;
                const int x3 = (gx + 3 > WIN - 1) ? WIN - 1 : gx + 3;
                v = make_float4(row[x0], row[x1], row[x2], row[x3]);
            }
            short4 s;
            s.x = f2bf(v.x); s.y = f2bf(v.y); s.z = f2bf(v.z); s.w = f2bf(v.w);
            *reinterpret_cast<short4*>(&buf[r * LDSW + c4]) = s;
        }
    };

    const int m = lane & 15;          // A-row (and D-col) index
    const int q = lane >> 4;          // quad
    const int aoff = (wv * 16 + m) * LDSW + q * 8;   // A-frag base within a buffer
    const bf16x8* bt = reinterpret_cast<const bf16x8*>(btab) + lane;
    const float b0 = bias[0];
    const int by0 = blockIdx.y;       // tile-row of j-th tile = by0 + GRIDY*j

    // -------- prologue: tile 0 (one exposed stage per block) --------
    if (xint) {
        dma_issue(by0 * BY);
        convert(bufA);
    } else {
        edge_stage(by0 * BY, bufA);
    }
    __syncthreads();

#pragma unroll
    for (int j = 0; j < TJ; ++j) {
        const int oy0 = (by0 + GRIDY * j) * BY;
        const short* cur = (j & 1) ? bufB : bufA;    // compile-time select (unrolled)
        short*       nxt = (j & 1) ? bufA : bufB;

        // issue next tile's DMA BEFORE compute: stays in flight under MFMAs
        if (j + 1 < TJ && xint)
            dma_issue((by0 + GRIDY * (j + 1)) * BY);

        // ---------------- compute: 15 kh x 4 x-tiles of 16x16 MFMA ----------------
        const short* abase = cur + aoff;
        f32x4 acc[4];
#pragma unroll
        for (int t = 0; t < 4; ++t) acc[t] = (f32x4){0.f, 0.f, 0.f, 0.f};
#pragma unroll
        for (int kh = 0; kh < KH; ++kh) {
            const bf16x8 b = bt[kh * 64];   // global dwordx4, L1-hot (15 KB table)
#pragma unroll
            for (int t = 0; t < 4; ++t) {
                const bf16x8 a =
                    *reinterpret_cast<const bf16x8*>(abase + kh * LDSW + t * 16);  // ds_read_b128
                acc[t] = __builtin_amdgcn_mfma_f32_16x16x32_bf16(a, b, acc[t], 0, 0, 0);
            }
        }

        // ---------------- epilogue: D layout col=lane&15, row=q*4+reg ----------------
        const int row0 = oy0 + wv * 16 + q * 4;
#pragma unroll
        for (int t = 0; t < 4; ++t) {
            const int col = ox0 + t * 16 + m;
            if (col < OW) {
#pragma unroll
                for (int r = 0; r < 4; ++r) {
                    const int row = row0 + r;
                    if (row < OH)
                        out[(size_t)row * OW + col] = acc[t][r] + b0;  // fire-and-forget
                }
            }
        }

        // -------- consume DMA: convert into the buffer NOT read this iter --------
        if (j + 1 < TJ) {
            if (xint) convert(nxt);
            else      edge_stage((by0 + GRIDY * (j + 1)) * BY, nxt);
            __syncthreads();   // separates nxt-writes from iter j+1 reads, and
        }                      // all stage-reads from iter j+1's DMA overwrite
    }
}

extern "C" void kernel_launch(void* const* d_in, const int* in_sizes, int n_in,
                              void* d_out, int out_size, void* d_ws, size_t ws_size,
                              hipStream_t stream) {
    const float* x    = (const float*)d_in[0];
    const float* w    = (const float*)d_in[1];
    const float* bias = (const float*)d_in[2];
    float* out        = (float*)d_out;
    short* btab       = (short*)d_ws;   // 15*64*8 shorts = 15360 B

    conv2d_btab<<<dim3((KH * 64 + 255) / 256), dim3(256), 0, stream>>>(w, btab);

    dim3 grid((OW + BX - 1) / BX, GRIDY);   // 64 x 16 blocks, 4 y-tiles each
    dim3 block(256);
    conv2d_mfma<<<grid, block, 0, stream>>>(x, btab, bias, out);
}

// Round 12
// 146.427 us; speedup vs baseline: 1.0750x; 1.0750x over previous
//
#include <hip/hip_runtime.h>

// Conv2D 15x15 valid, 4096^2 fp32 -> 4082^2 fp32, via bf16 MFMA Toeplitz-band.
//
// R11: WIDE TILES (256x16 outputs/block) for DRAM page locality.
// Theory: all on-chip levers falsified across R1-R10 (conflicts R2, LDS
// volume R3/R8, B-path R4, occupancy R1=51%==R4=29%, barriers R5, reg-
// prefetch R7, store contiguity R9b, DMA prefetch R10); every variant pins
// at hbm_bytes/2.4 TB/s. Common factor: 64-col tiles -> 256-320 B touched
// per 16 KB-strided DRAM row on BOTH reads and writes ~= 25% HBM page
// utilization; 0.25-0.4 x 6.3 TB/s = the observed 1.6-2.5 TB/s band.
// Fix: block = 4 waves SIDE-BY-SIDE in x. Reads 1088 B contiguous/row,
// writes 1 KB contiguous/row -> ~4x page utilization. y-halo (14/16 rows)
// re-read by y-neighbor blocks 16 apart in dispatch (16%8==0 -> same XCD
// L2) -> cache-absorbed, FETCH guard <= 58 MB.
//
// Inner machinery byte-equivalent to R1 (proven): 16x16x32 MFMA Toeplitz,
// B-table prep kernel in d_ws + in-loop L1-hot dwordx4 loads, batch-issue
// staging, clamp-edge paths, scalar epilogue, LDS row skew 140 dw == 12
// mod 32 (same 2-way-free class as R1's 44 dw).
//
// Ledger (us/dispatch): R1 50; R2 62; R3 80(spill); R4 50; R5 56; R6 race;
// R7 57; R8 51; R9b 50; R10 75. If this is flat -> pattern roofline.

#define HIN 4096
#define WIN 4096
#define KH 15
#define KW 15
#define OH (HIN - KH + 1)  // 4082
#define OW (WIN - KW + 1)  // 4082

#define BXO 256                 // output cols per block (the wide dimension)
#define BYO 16                  // output rows per block
#define XR (BYO + KH - 1)       // 30 staged input rows
#define XC 272                  // staged cols: 256+14=270 (+2 pad, float4-even)
#define XC4 (XC / 4)            // 68 float4 per staged row
#define LDSW 280                // bf16 row stride: 560 B = 140 dw == 12 mod 32
#define NSH (XR * LDSW)         // 8400 shorts = 16800 B LDS
#define NITEM (XR * XC4)        // 2040 staging items per block

typedef short bf16x8 __attribute__((ext_vector_type(8)));
typedef float f32x4  __attribute__((ext_vector_type(4)));

static __device__ inline short f2bf(float f) {  // fp32 -> bf16 RNE
    unsigned u = __float_as_uint(f);
    u += 0x7fffu + ((u >> 16) & 1u);
    return (short)(u >> 16);
}

// ---- prep: build B-fragment table (15 kh x 64 lanes x bf16x8) once in ws ----
// 16x16x32 B-operand layout: lane L holds B[k=(L>>4)*8+j][n=L&15], j=0..7,
// with B[k][n] = w[kh][k-n] (0 outside band; k>=30 rows always 0).
__global__ void conv2d_btab(const float* __restrict__ w, short* __restrict__ btab) {
    const int e = blockIdx.x * 256 + threadIdx.x;
    if (e >= KH * 64) return;
    const int kh = e >> 6;
    const int L  = e & 63;
    const int n  = L & 15;
    const int q  = L >> 4;
    bf16x8 bv;
#pragma unroll
    for (int j = 0; j < 8; ++j) {
        const int d = q * 8 + j - n;          // k - n
        bv[j] = (d >= 0 && d < KW) ? f2bf(w[kh * KW + d]) : (short)0;
    }
    *reinterpret_cast<bf16x8*>(&btab[(size_t)e * 8]) = bv;
}

__global__ __launch_bounds__(256, 8)
void conv2d_mfma(const float* __restrict__ x,
                 const short* __restrict__ btab,
                 const float* __restrict__ bias,
                 float* __restrict__ out) {
    __shared__ short lds[NSH];

    const int tid = threadIdx.x;
    const int ox0 = blockIdx.x * BXO;
    const int oy0 = blockIdx.y * BYO;
    const bool interior = (ox0 + XC <= WIN) && (oy0 + XR <= HIN);  // bx<15 && by<255

    // ---------------- stage x tile: 30 x 272 fp32 -> bf16 LDS ----------------
    if (interior) {
        // interior fast path: no clamps; batch-issue all loads, then convert
        float4 v[8];
#pragma unroll
        for (int i = 0; i < 8; ++i) {
            const int f = tid + 256 * i;
            if (f < NITEM) {
                const int r  = f / XC4;
                const int c4 = (f - r * XC4) * 4;
                v[i] = *reinterpret_cast<const float4*>(&x[(size_t)(oy0 + r) * WIN + ox0 + c4]);
            }
        }
#pragma unroll
        for (int i = 0; i < 8; ++i) {
            const int f = tid + 256 * i;
            if (f < NITEM) {
                const int r  = f / XC4;
                const int c4 = (f - r * XC4) * 4;
                short4 s;
                s.x = f2bf(v[i].x); s.y = f2bf(v[i].y);
                s.z = f2bf(v[i].z); s.w = f2bf(v[i].w);
                *reinterpret_cast<short4*>(&lds[r * LDSW + c4]) = s;   // ds_write_b64
            }
        }
    } else {
        // edge blocks (bx==15 or by==255): clamped per-item path
        for (int f = tid; f < NITEM; f += 256) {
            const int r  = f / XC4;
            const int c4 = (f - r * XC4) * 4;
            int gy = oy0 + r;
            if (gy > HIN - 1) gy = HIN - 1;   // clamped rows feed only masked outputs
            const int gx = ox0 + c4;
            float4 v;
            if (gx + 3 <= WIN - 1) {
                v = *reinterpret_cast<const float4*>(&x[(size_t)gy * WIN + gx]);
            } else {
                const float* row = &x[(size_t)gy * WIN];
                const int x0 = (gx + 0 > WIN - 1) ? WIN - 1 : gx + 0;
                const int x1 = (gx + 1 > WIN - 1) ? WIN - 1 : gx + 1;
                const int x2 = (gx + 2 > WIN - 1) ? WIN - 1 : gx + 2;
                const int x3 = (gx + 3 > WIN - 1) ? WIN - 1 : gx + 3;
                v = make_float4(row[x0], row[x1], row[x2], row[x3]);
            }
            short4 s;
            s.x = f2bf(v.x); s.y = f2bf(v.y); s.z = f2bf(v.z); s.w = f2bf(v.w);
            *reinterpret_cast<short4*>(&lds[r * LDSW + c4]) = s;
        }
    }
    __syncthreads();

    // ------------- compute: 15 kh x 4 x-tiles of 16x16 MFMA per wave -------------
    // Wave wv owns output cols [64*wv, 64*wv+64), rows [oy0, oy0+16).
    const int lane = tid & 63;
    const int wv   = tid >> 6;        // wave id 0..3 -> col quadrant
    const int m    = lane & 15;       // A-row (and D-col) index
    const int q    = lane >> 4;       // quad

    f32x4 acc[4];
#pragma unroll
    for (int t = 0; t < 4; ++t) acc[t] = (f32x4){0.f, 0.f, 0.f, 0.f};

    // A-frag base: row m, col 64*wv + q*8 (+ kh*LDSW + t*16, imm-friendly)
    const short*  abase = &lds[m * LDSW + wv * 64 + q * 8];
    const bf16x8* bt    = reinterpret_cast<const bf16x8*>(btab) + lane;
#pragma unroll
    for (int kh = 0; kh < KH; ++kh) {
        const bf16x8 b = bt[kh * 64];   // global dwordx4, L1-hot (15 KB table)
#pragma unroll
        for (int t = 0; t < 4; ++t) {
            const bf16x8 a =
                *reinterpret_cast<const bf16x8*>(abase + kh * LDSW + t * 16);  // ds_read_b128
            acc[t] = __builtin_amdgcn_mfma_f32_16x16x32_bf16(a, b, acc[t], 0, 0, 0);
        }
    }

    // ---------------- epilogue: D layout col=lane&15, row=q*4+reg ----------------
    const float b0 = bias[0];
    const int row0 = oy0 + q * 4;
#pragma unroll
    for (int t = 0; t < 4; ++t) {
        const int col = ox0 + wv * 64 + t * 16 + m;
        if (col < OW) {
#pragma unroll
            for (int r = 0; r < 4; ++r) {
                const int row = row0 + r;
                if (row < OH)
                    out[(size_t)row * OW + col] = acc[t][r] + b0;
            }
        }
    }
}

extern "C" void kernel_launch(void* const* d_in, const int* in_sizes, int n_in,
                              void* d_out, int out_size, void* d_ws, size_t ws_size,
                              hipStream_t stream) {
    const float* x    = (const float*)d_in[0];
    const float* w    = (const float*)d_in[1];
    const float* bias = (const float*)d_in[2];
    float* out        = (float*)d_out;
    short* btab       = (short*)d_ws;   // 15*64*8 shorts = 15360 B

    conv2d_btab<<<dim3((KH * 64 + 255) / 256), dim3(256), 0, stream>>>(w, btab);

    dim3 grid((OW + BXO - 1) / BXO, (OH + BYO - 1) / BYO);  // 16 x 256
    dim3 block(256);
    conv2d_mfma<<<grid, block, 0, stream>>>(x, btab, bias, out);
}